// Round 8
// baseline (145.462 us; speedup 1.0000x reference)
//
#include <hip/hip_runtime.h>

#define E_TOTAL 800000
#define NN      50000
#define ND      64
#define ED      32
#define HD      128
#define OD      64
#define IND     160      // ED + 2*ND
#define MT      128      // edges per block
#define NTHREADS 512

typedef __attribute__((ext_vector_type(8))) short          short8;
typedef __attribute__((ext_vector_type(4))) float          f32x4;
typedef __attribute__((ext_vector_type(8))) unsigned short u16x8;
typedef __attribute__((ext_vector_type(4))) unsigned short u16x4;
typedef __attribute__((ext_vector_type(2))) unsigned int   u32x2;

__device__ __forceinline__ unsigned short f2bf(float f) {
  union { float f; unsigned u; } v; v.f = f;
  unsigned r = v.u + 0x7fffu + ((v.u >> 16) & 1u);   // RNE
  return (unsigned short)(r >> 16);
}

// ===================== LDS =====================
// W1: 40 A-frags (1024B each) = 40960 B.
// Hs: per-wave redistribute scratch: 16 rows x 20 dw (80B, padded from 64B to
//     break bank alignment) = 1280 B/wave x 8 waves = 10240 B.
// Total 51200 B -> 3 blocks/CU. No H tile buffer: layer-1 output lives in
// C-registers and round-trips 1 KiB at a time through the wave-private scratch.
#define W1_FRAGS 40
#define SCR_DW_WAVE 320                  // 16 * 20 dw
#define SMEM_BYTES (W1_FRAGS * 1024 + 8 * SCR_DW_WAVE * 4)   // 51200

// ---------- prepass: f32 -> bf16 node table ----------
__global__ void cvt_nodes(const float* __restrict__ in, unsigned short* __restrict__ out, int n4) {
  int i = blockIdx.x * blockDim.x + threadIdx.x;
  const int stride = gridDim.x * blockDim.x;
  for (; i < n4; i += stride) {
    float4 v = ((const float4*)in)[i];
    u16x4 o = { f2bf(v.x), f2bf(v.y), f2bf(v.z), f2bf(v.w) };
    ((u16x4*)out)[i] = o;
  }
}

// ---------- prepass: pack W1 (A-operand frags for swapped product) ----------
// frag f = ks*8 + nt: lane l, reg j holds W1[k=ks*32+(l>>4)*8+j][n=nt*16+(l&15)]
__global__ void pack_w1(const float* __restrict__ w, unsigned short* __restrict__ out) {
  int i = blockIdx.x * blockDim.x + threadIdx.x;
  if (i >= HD * IND) return;
  int j = i & 7, l = (i >> 3) & 63, f = i >> 9;   // f in [0,40)
  int ks = f >> 3, t = f & 7;
  int k = ks * 32 + (l >> 4) * 8 + j;
  int n = t * 16 + (l & 15);
  out[i] = f2bf(w[k * HD + n]);
}

// ---------- prepass: pack W2 (A-operand frags) ----------
__global__ void pack_w2(const float* __restrict__ w, unsigned short* __restrict__ out) {
  int i = blockIdx.x * blockDim.x + threadIdx.x;
  if (i >= OD * HD) return;
  int j = i & 7, l = (i >> 3) & 63, f = i >> 9;   // f in [0,16)
  int ks = f >> 2, t = f & 3;
  int k = ks * 32 + (l >> 4) * 8 + j;
  int n = t * 16 + (l & 15);
  out[i] = f2bf(w[k * OD + n]);
}

// ---------- main fused kernel: swapped-operand MFMA, 3 blocks/CU ----------
// Layer 1 computes H^T tiles: C = mfma(W1frag, Xfrag): lane l holds
// H[m = l&15][n = nt*16 + (l>>4)*4 + r]. Bias/relu/cvt in-register, then a
// 1 KiB wave-private LDS scratch converts C-layout to the B-frag layout for
// layer 2: OUT^T = mfma(W2frag, Hfrag) -> per-lane contiguous float4 stores.
__global__ __launch_bounds__(NTHREADS, 6)
void edge_mlp(const int* __restrict__ eidx,
              const float* __restrict__ ef,
              const unsigned short* __restrict__ nbf,
              const unsigned short* __restrict__ w1p,
              const unsigned short* __restrict__ w2p,
              const float* __restrict__ b1,
              const float* __restrict__ b2,
              float* __restrict__ out)
{
  extern __shared__ unsigned short sm[];
  unsigned short* W1 = sm;                               // 40 frags
  unsigned int*   Hs = (unsigned int*)(sm + W1_FRAGS * 512);  // scratch (dw)

  const int tid  = threadIdx.x;
  const int wid  = tid >> 6;
  const int lane = tid & 63;
  const int lq   = lane >> 4;
  const int lr   = lane & 15;
  const long e   = (long)blockIdx.x * MT + wid * 16 + lr;   // this lane's edge

  // ---- index loads first (head of dependent chain)
  int si = eidx[e];
  int ti = eidx[E_TOTAL + e];

  // ---- edge features (B-frag ks=0 data: lane holds X[m=lr][k=lq*8+j])
  const float4 e0v = *(const float4*)(ef + e * ED + lq * 8);
  const float4 e1v = *(const float4*)(ef + e * ED + lq * 8 + 4);

  // ---- W1 chunk loads (linear, coalesced)
  u16x8 wv[5];
  #pragma unroll
  for (int c = 0; c < 5; ++c)
    wv[c] = *(const u16x8*)(w1p + (tid + c * NTHREADS) * 8);

  // ---- node-row gathers into B-frag registers
  si = si < 0 ? 0 : (si >= NN ? NN - 1 : si);
  ti = ti < 0 ? 0 : (ti >= NN ? NN - 1 : ti);
  const unsigned short* sr = nbf + (long)si * ND;
  const unsigned short* tr = nbf + (long)ti * ND;
  const short8 g0 = *(const short8*)(sr + lq * 8);
  const short8 g1 = *(const short8*)(sr + 32 + lq * 8);
  const short8 g2 = *(const short8*)(tr + lq * 8);
  const short8 g3 = *(const short8*)(tr + 32 + lq * 8);

  // ---- W1 -> LDS (conflict-free b128)
  #pragma unroll
  for (int c = 0; c < 5; ++c)
    *(u16x8*)(W1 + (tid + c * NTHREADS) * 8) = wv[c];

  // ---- only barrier: W1 visible; lgkm-only wait (gathers stay in flight)
  asm volatile("s_waitcnt lgkmcnt(0)" ::: "memory");
  __builtin_amdgcn_s_barrier();

  // ---- B-frag ks=0 from edge features
  short8 aef;
  aef[0] = (short)f2bf(e0v.x); aef[1] = (short)f2bf(e0v.y);
  aef[2] = (short)f2bf(e0v.z); aef[3] = (short)f2bf(e0v.w);
  aef[4] = (short)f2bf(e1v.x); aef[5] = (short)f2bf(e1v.y);
  aef[6] = (short)f2bf(e1v.z); aef[7] = (short)f2bf(e1v.w);

  // ---- layer 1 (swapped): H^T tiles; A = W1 frag (LDS), B = gathers (regs)
  f32x4 acc[8];
  #pragma unroll
  for (int t = 0; t < 8; ++t) acc[t] = (f32x4)0.0f;

  #define L1STEP(BV, KS)                                                        \
    _Pragma("unroll")                                                           \
    for (int nt = 0; nt < 8; ++nt) {                                            \
      const short8 a = *(const short8*)(W1 + ((KS) * 8 + nt) * 512 + lane * 8); \
      acc[nt] = __builtin_amdgcn_mfma_f32_16x16x32_bf16(a, BV, acc[nt], 0, 0, 0); \
    }
  L1STEP(g0, 1)
  L1STEP(g1, 2)
  L1STEP(g2, 3)
  L1STEP(g3, 4)
  L1STEP(aef, 0)
  #undef L1STEP

  // ---- per-ks: bias+relu+pack -> scratch -> B-frag -> 4 layer-2 MFMAs
  unsigned int* scr = Hs + wid * SCR_DW_WAVE;   // wave-private
  f32x4 acc2[4];
  #pragma unroll
  for (int t = 0; t < 4; ++t) acc2[t] = (f32x4)0.0f;

  #pragma unroll
  for (int ks = 0; ks < 4; ++ks) {
    #pragma unroll
    for (int h = 0; h < 2; ++h) {
      const int nt = 2 * ks + h;
      const float4 bq = *(const float4*)(b1 + nt * 16 + lq * 4);
      const float h0 = fmaxf(acc[nt][0] + bq.x, 0.0f);
      const float h1 = fmaxf(acc[nt][1] + bq.y, 0.0f);
      const float h2 = fmaxf(acc[nt][2] + bq.z, 0.0f);
      const float h3 = fmaxf(acc[nt][3] + bq.w, 0.0f);
      u32x2 wpair;
      wpair[0] = (unsigned)f2bf(h0) | ((unsigned)f2bf(h1) << 16);
      wpair[1] = (unsigned)f2bf(h2) | ((unsigned)f2bf(h3) << 16);
      // H[m=lr][k_local = 16h + lq*4 + {0..3}] -> dw words 8h + lq*2 + {0,1}
      *(u32x2*)(scr + lr * 20 + 8 * h + lq * 2) = wpair;
    }
    // B-frag read: lane l takes H[m=lr][k_local = lq*8 + j]  (16B aligned)
    const short8 a2 = *(const short8*)((const unsigned short*)(scr + lr * 20 + lq * 4));
    #pragma unroll
    for (int t = 0; t < 4; ++t) {
      const short8 wa = *(const short8*)(w2p + ((ks * 4 + t) * 64 + lane) * 8);
      acc2[t] = __builtin_amdgcn_mfma_f32_16x16x32_bf16(wa, a2, acc2[t], 0, 0, 0);
    }
  }

  // ---- epilogue: OUT^T C-tiles -> per-lane contiguous float4 stores
  // lane l holds OUT[m = lr][n = t*16 + lq*4 + {0..3}]
  #pragma unroll
  for (int t = 0; t < 4; ++t) {
    const float4 bq = *(const float4*)(b2 + t * 16 + lq * 4);
    float4 o;
    o.x = acc2[t][0] + bq.x;
    o.y = acc2[t][1] + bq.y;
    o.z = acc2[t][2] + bq.z;
    o.w = acc2[t][3] + bq.w;
    *(float4*)(out + e * OD + t * 16 + lq * 4) = o;
  }
}

extern "C" void kernel_launch(void* const* d_in, const int* in_sizes, int n_in,
                              void* d_out, int out_size, void* d_ws, size_t ws_size,
                              hipStream_t stream) {
  const int*   eidx = (const int*)d_in[0];      // (2, E) int32
  const float* nf   = (const float*)d_in[1];    // (NN, 64)
  const float* ef   = (const float*)d_in[2];    // (E, 32)
  const float* w1   = (const float*)d_in[3];    // (160, 128)
  const float* b1   = (const float*)d_in[4];    // (128,)
  const float* w2   = (const float*)d_in[5];    // (128, 64)
  const float* b2   = (const float*)d_in[6];    // (64,)
  float*       out  = (float*)d_out;            // (E, 64)

  unsigned short* nbf = (unsigned short*)d_ws;            // NN*ND
  unsigned short* w1p = nbf + (long)NN * ND;              // HD*IND
  unsigned short* w2p = w1p + (long)HD * IND;             // OD*HD

  cvt_nodes<<<1024, 256, 0, stream>>>(nf, nbf, (NN * ND) / 4);
  pack_w1<<<(HD * IND + 255) / 256, 256, 0, stream>>>(w1, w1p);
  pack_w2<<<(OD * HD + 255) / 256, 256, 0, stream>>>(w2, w2p);

  hipFuncSetAttribute((const void*)edge_mlp,
                      hipFuncAttributeMaxDynamicSharedMemorySize, SMEM_BYTES);
  edge_mlp<<<E_TOTAL / MT, NTHREADS, SMEM_BYTES, stream>>>(
      eidx, ef, nbf, w1p, w2p, b1, b2, out);
}

// Round 9
// 134.478 us; speedup vs baseline: 1.0817x; 1.0817x over previous
//
#include <hip/hip_runtime.h>

#define E_TOTAL 800000
#define NN      50000
#define ND      64
#define ED      32
#define HD      128
#define OD      64
#define IND     160      // ED + 2*ND
#define MT      128      // edges per block
#define NTHREADS 512

typedef __attribute__((ext_vector_type(8))) short          short8;
typedef __attribute__((ext_vector_type(4))) float          f32x4;
typedef __attribute__((ext_vector_type(8))) unsigned short u16x8;
typedef __attribute__((ext_vector_type(4))) unsigned short u16x4;

__device__ __forceinline__ unsigned short f2bf(float f) {
  union { float f; unsigned u; } v; v.f = f;
  unsigned r = v.u + 0x7fffu + ((v.u >> 16) & 1u);   // RNE
  return (unsigned short)(r >> 16);
}

// async 16B/lane global->LDS: lds dest = wave-uniform base + lane*16,
// global src = per-lane address. Cannot be sunk by the compiler (no dest reg).
__device__ __forceinline__ void gload_lds16(const void* g, void* l) {
  __builtin_amdgcn_global_load_lds(
      (const __attribute__((address_space(1))) unsigned int*)g,
      (__attribute__((address_space(3))) unsigned int*)l, 16, 0, 0);
}

// ===================== LDS =====================
// X: 32 frags (wave w owns frags [w*4, w*4+4) = its 4 node-gather frags;
//    H overlays them after layer 1 — wave-private, no barrier).
// W1: 40 frags (shared, staged once via global_load_lds).
// frag = 1024 B; lane l's 16B at frag*1024 + l*16 -> conflict-free b128.
#define X_FRAGS  32
#define SMEM_U16 ((X_FRAGS + 40) * 512)
#define SMEM_BYTES (SMEM_U16 * 2)           // 73728 B -> 2 blocks/CU

// ---------- prepass: f32 -> bf16 node table ----------
__global__ void cvt_nodes(const float* __restrict__ in, unsigned short* __restrict__ out, int n4) {
  int i = blockIdx.x * blockDim.x + threadIdx.x;
  const int stride = gridDim.x * blockDim.x;
  for (; i < n4; i += stride) {
    float4 v = ((const float4*)in)[i];
    u16x4 o = { f2bf(v.x), f2bf(v.y), f2bf(v.z), f2bf(v.w) };
    ((u16x4*)out)[i] = o;
  }
}

// ---------- prepass: pack W1 into B-fragment order ----------
__global__ void pack_w1(const float* __restrict__ w, unsigned short* __restrict__ out) {
  int i = blockIdx.x * blockDim.x + threadIdx.x;
  if (i >= HD * IND) return;
  int j = i & 7, l = (i >> 3) & 63, f = i >> 9;   // f in [0,40)
  int ks = f >> 3, t = f & 7;
  int k = ks * 32 + (l >> 4) * 8 + j;
  int n = t * 16 + (l & 15);
  out[i] = f2bf(w[k * HD + n]);
}

// ---------- prepass: pack W2 into B-fragment order ----------
__global__ void pack_w2(const float* __restrict__ w, unsigned short* __restrict__ out) {
  int i = blockIdx.x * blockDim.x + threadIdx.x;
  if (i >= OD * HD) return;
  int j = i & 7, l = (i >> 3) & 63, f = i >> 9;   // f in [0,16)
  int ks = f >> 2, t = f & 3;
  int k = ks * 32 + (l >> 4) * 8 + j;
  int n = t * 16 + (l & 15);
  out[i] = f2bf(w[k * OD + n]);
}

// ---------- main fused kernel: async-staged, one barrier ----------
__global__ __launch_bounds__(NTHREADS, 4)
void edge_mlp(const int* __restrict__ eidx,
              const float* __restrict__ ef,
              const unsigned short* __restrict__ nbf,
              const unsigned short* __restrict__ w1p,
              const unsigned short* __restrict__ w2p,
              const float* __restrict__ b1,
              const float* __restrict__ b2,
              float* __restrict__ out)
{
  extern __shared__ unsigned short sm[];
  unsigned short* Xs = sm;                  // 32 frags (H overlays after L1)
  unsigned short* W1 = sm + X_FRAGS * 512;  // 40 frags

  const int tid  = threadIdx.x;
  const int wid  = tid >> 6;
  const int lane = tid & 63;
  const int lq   = lane >> 4;
  const int lr   = lane & 15;
  const long e   = (long)blockIdx.x * MT + wid * 16 + lr;   // this lane's edge

  // ---- 1) index loads (head of the dependent chain)
  int si = eidx[e];
  int ti = eidx[E_TOTAL + e];

  // ---- 2) W1 staging: 5 async frag-copies per wave, in flight immediately
  #pragma unroll
  for (int c = 0; c < 5; ++c) {
    const int f = wid * 5 + c;
    gload_lds16(w1p + f * 512 + lane * 8, W1 + f * 512);
  }

  // ---- 3) edge features (register path; ks=0 A-frag, converted later)
  const float4 e0v = *(const float4*)(ef + e * ED + lq * 8);
  const float4 e1v = *(const float4*)(ef + e * ED + lq * 8 + 4);

  // ---- 4) biases
  float b1v[8];
  #pragma unroll
  for (int t = 0; t < 8; ++t) b1v[t] = b1[t * 16 + lr];
  float b2v[4];
  #pragma unroll
  for (int t = 0; t < 4; ++t) b2v[t] = b2[t * 16 + lr];

  // ---- 5) node gathers: 4 async frag-copies per wave, per-lane src addresses.
  //        (waits the idx vmcnt only; W1/ef stay in flight)
  si = si < 0 ? 0 : (si >= NN ? NN - 1 : si);
  ti = ti < 0 ? 0 : (ti >= NN ? NN - 1 : ti);
  const unsigned short* sr = nbf + (long)si * ND;
  const unsigned short* tr = nbf + (long)ti * ND;
  unsigned short* xbase = Xs + (wid * 4) * 512;
  gload_lds16(sr + lq * 8,      xbase);            // frag wid*4+0: src k[0,32)
  gload_lds16(sr + 32 + lq * 8, xbase + 512);      // frag wid*4+1: src k[32,64)
  gload_lds16(tr + lq * 8,      xbase + 1024);     // frag wid*4+2: tgt k[0,32)
  gload_lds16(tr + 32 + lq * 8, xbase + 1536);     // frag wid*4+3: tgt k[32,64)

  // ---- 6) single drain + single barrier (X own-wave + W1 shared)
  asm volatile("s_waitcnt vmcnt(0)" ::: "memory");
  __builtin_amdgcn_s_barrier();
  __builtin_amdgcn_sched_barrier(0);

  // ---- A-frag ks=0 from edge features
  short8 aef;
  aef[0] = (short)f2bf(e0v.x); aef[1] = (short)f2bf(e0v.y);
  aef[2] = (short)f2bf(e0v.z); aef[3] = (short)f2bf(e0v.w);
  aef[4] = (short)f2bf(e1v.x); aef[5] = (short)f2bf(e1v.y);
  aef[6] = (short)f2bf(e1v.z); aef[7] = (short)f2bf(e1v.w);

  // ---- layer 1: H[128x128] = X @ W1  (A: own X frags / aef; B: shared W1)
  f32x4 acc[8];
  #pragma unroll
  for (int t = 0; t < 8; ++t) acc[t] = (f32x4)0.0f;

  #pragma unroll
  for (int kk = 0; kk < 4; ++kk) {                    // ks = 1..4
    const short8 a = *(const short8*)(xbase + kk * 512 + lane * 8);
    #pragma unroll
    for (int t = 0; t < 8; ++t) {
      const short8 b = *(const short8*)(W1 + ((kk + 1) * 8 + t) * 512 + lane * 8);
      acc[t] = __builtin_amdgcn_mfma_f32_16x16x32_bf16(a, b, acc[t], 0, 0, 0);
    }
  }
  #pragma unroll
  for (int t = 0; t < 8; ++t) {                       // ks = 0 (edge feats)
    const short8 b = *(const short8*)(W1 + (0 * 8 + t) * 512 + lane * 8);
    acc[t] = __builtin_amdgcn_mfma_f32_16x16x32_bf16(aef, b, acc[t], 0, 0, 0);
  }

  // ---- relu + bias -> H A-frags overlaying own X frags (wave-private;
  //      DS ops of one wave are processed in order -> no barrier)
  #pragma unroll
  for (int t = 0; t < 8; ++t) {
    #pragma unroll
    for (int r = 0; r < 4; ++r) {
      float h = acc[t][r] + b1v[t];
      h = h > 0.0f ? h : 0.0f;
      const int k    = t * 16 + lr;
      const int frag = (k >> 5);
      const int l2   = (((k >> 3) & 3) << 4) + lq * 4 + r;
      xbase[frag * 512 + l2 * 8 + (k & 7)] = f2bf(h);
    }
  }

  // ---- read back own H A-frags
  short8 a2[4];
  #pragma unroll
  for (int ks = 0; ks < 4; ++ks)
    a2[ks] = *(const short8*)(xbase + ks * 512 + lane * 8);

  // ---- layer 2: OUT[128x64] = H @ W2 (B frags from global, L1/L2-hot)
  f32x4 acc2[4];
  #pragma unroll
  for (int t = 0; t < 4; ++t) acc2[t] = (f32x4)0.0f;
  #pragma unroll
  for (int t = 0; t < 4; ++t) {
    #pragma unroll
    for (int ks = 0; ks < 4; ++ks) {
      const short8 b = *(const short8*)(w2p + ((ks * 4 + t) * 64 + lane) * 8);
      acc2[t] = __builtin_amdgcn_mfma_f32_16x16x32_bf16(a2[ks], b, acc2[t], 0, 0, 0);
    }
  }

  // ---- epilogue: bias + f32 store
  const long mbase = (long)blockIdx.x * MT + wid * 16 + lq * 4;
  #pragma unroll
  for (int t = 0; t < 4; ++t) {
    #pragma unroll
    for (int r = 0; r < 4; ++r) {
      out[(mbase + r) * OD + t * 16 + lr] = acc2[t][r] + b2v[t];
    }
  }
}

extern "C" void kernel_launch(void* const* d_in, const int* in_sizes, int n_in,
                              void* d_out, int out_size, void* d_ws, size_t ws_size,
                              hipStream_t stream) {
  const int*   eidx = (const int*)d_in[0];      // (2, E) int32
  const float* nf   = (const float*)d_in[1];    // (NN, 64)
  const float* ef   = (const float*)d_in[2];    // (E, 32)
  const float* w1   = (const float*)d_in[3];    // (160, 128)
  const float* b1   = (const float*)d_in[4];    // (128,)
  const float* w2   = (const float*)d_in[5];    // (128, 64)
  const float* b2   = (const float*)d_in[6];    // (64,)
  float*       out  = (float*)d_out;            // (E, 64)

  unsigned short* nbf = (unsigned short*)d_ws;            // NN*ND
  unsigned short* w1p = nbf + (long)NN * ND;              // HD*IND
  unsigned short* w2p = w1p + (long)HD * IND;             // OD*HD

  cvt_nodes<<<1024, 256, 0, stream>>>(nf, nbf, (NN * ND) / 4);
  pack_w1<<<(HD * IND + 255) / 256, 256, 0, stream>>>(w1, w1p);
  pack_w2<<<(OD * HD + 255) / 256, 256, 0, stream>>>(w2, w2p);

  hipFuncSetAttribute((const void*)edge_mlp,
                      hipFuncAttributeMaxDynamicSharedMemorySize, SMEM_BYTES);
  edge_mlp<<<E_TOTAL / MT, NTHREADS, SMEM_BYTES, stream>>>(
      eidx, ef, nbf, w1p, w2p, b1, b2, out);
}